// Round 12
// baseline (350.710 us; speedup 1.0000x reference)
//
#include <hip/hip_runtime.h>

// Problem constants
#define B_ 512
#define L_ 256
#define D_ 1024
#define H_ 16
#define DK_ 64
#define DV_ 64
// TEMP = sqrt(1024) = 32 exactly (folded into Aq in k_proj)

typedef float f32x4 __attribute__((ext_vector_type(4)));
typedef __bf16 bf16x8 __attribute__((ext_vector_type(8)));

#define MFMA16(a, b, c) __builtin_amdgcn_mfma_f32_16x16x32_bf16((a), (b), (c), 0, 0, 0)

__device__ inline bf16x8 cvt8(f32x4 a, f32x4 b) {
  bf16x8 r;
  r[0] = (__bf16)a[0]; r[1] = (__bf16)a[1]; r[2] = (__bf16)a[2]; r[3] = (__bf16)a[3];
  r[4] = (__bf16)b[0]; r[5] = (__bf16)b[1]; r[6] = (__bf16)b[2]; r[7] = (__bf16)b[3];
  return r;
}

// nontemporal loads for single-use streams (k, v): bypass L2 allocation
__device__ inline f32x4 ntl4(const float* p) {
  return __builtin_nontemporal_load((const f32x4*)p);
}
__device__ inline float ntl1(const float* p) {
  return __builtin_nontemporal_load(p);
}

// ---------------------------------------------------------------------------
// K1: fused q-proj + Wk-proj.  grid (32 m-tiles, 16 h), block 256 (4 waves).
// ---------------------------------------------------------------------------
__global__ __launch_bounds__(256) void k_proj(const float* __restrict__ q,
                                              const float* __restrict__ Wq,
                                              const float* __restrict__ Wk,
                                              __bf16* __restrict__ Aq) {
  __shared__ __bf16 hq_lds[16][80];  // row stride 160B (16B-mult)
  int tid = threadIdx.x, lane = tid & 63, wid = tid >> 6;
  int r16 = lane & 15, g = lane >> 4;
  int m0 = blockIdx.x * 16, h = blockIdx.y;

  // ---- Step 1: wave wid computes kk-ntile wid*16
  {
    const float* arow = q  + (size_t)(m0 + r16) * D_;
    const float* brow = Wq + (size_t)(h * DK_ + wid * 16 + r16) * D_;
    f32x4 acc = {0.f, 0.f, 0.f, 0.f};
    for (int ks = 0; ks < D_ / 32; ++ks) {
      int k0 = ks * 32 + g * 8;
      f32x4 a0 = *(const f32x4*)(arow + k0);
      f32x4 a1 = *(const f32x4*)(arow + k0 + 4);
      f32x4 b0 = *(const f32x4*)(brow + k0);
      f32x4 b1 = *(const f32x4*)(brow + k0 + 4);
      acc = MFMA16(cvt8(a0, a1), cvt8(b0, b1), acc);
    }
#pragma unroll
    for (int r = 0; r < 4; ++r)
      hq_lds[g * 4 + r][wid * 16 + r16] = (__bf16)acc[r];
  }
  __syncthreads();

  // ---- Step 2: wave wid owns d-cols [wid*256, +256) = 16 ntiles
  const float* bcolBase = Wk + (size_t)h * DK_ * D_;
  for (int nt = 0; nt < 16; ++nt) {
    int n0 = wid * 256 + nt * 16;
    const float* bcol = bcolBase + n0 + r16;  // + k*D_
    f32x4 acc = {0.f, 0.f, 0.f, 0.f};
#pragma unroll
    for (int ks = 0; ks < 2; ++ks) {
      int k0 = ks * 32 + g * 8;
      bf16x8 a = *(const bf16x8*)(&hq_lds[r16][k0]);
      f32x4 c0, c1;
#pragma unroll
      for (int j = 0; j < 4; ++j) c0[j] = bcol[(size_t)(k0 + j) * D_];
#pragma unroll
      for (int j = 0; j < 4; ++j) c1[j] = bcol[(size_t)(k0 + 4 + j) * D_];
      acc = MFMA16(a, cvt8(c0, c1), acc);
    }
#pragma unroll
    for (int r = 0; r < 4; ++r) {
      int m = m0 + g * 4 + r;
      Aq[(size_t)m * (H_ * D_) + (size_t)h * D_ + n0 + r16] = (__bf16)(acc[r] * 0.03125f);
    }
  }
}

// ---------------------------------------------------------------------------
// K2: scores[b, h, l] = Aq[b,h,:] . k[b,l,:]   (R10 body + nontemporal k)
// grid (4, 512): x = l-quarter, y = b. block 256 (4 waves), 32 waves/CU.
// ---------------------------------------------------------------------------
__global__ __launch_bounds__(256) void k_score(const float* __restrict__ kg,
                                               const __bf16* __restrict__ Aq,
                                               float* __restrict__ sc) {
  int tid = threadIdx.x, lane = tid & 63, wv = tid >> 6;
  int r16 = lane & 15, g = lane >> 4;
  int b = blockIdx.y;
  int l0 = blockIdx.x * 64 + wv * 16;
  const __bf16* AqB = Aq + (size_t)b * H_ * D_;
  const float*  kR  = kg + ((size_t)b * L_ + l0 + r16) * D_;
  f32x4 acc = {0.f, 0.f, 0.f, 0.f};
#pragma unroll 4
  for (int ks = 0; ks < D_ / 32; ++ks) {
    int k0 = ks * 32 + g * 8;
    bf16x8 a = *(const bf16x8*)(AqB + (size_t)r16 * D_ + k0);
    f32x4 b0 = ntl4(kR + k0);
    f32x4 b1 = ntl4(kR + k0 + 4);
    acc = MFMA16(a, cvt8(b0, b1), acc);
  }
#pragma unroll
  for (int r = 0; r < 4; ++r) {
    int h = g * 4 + r;
    sc[((size_t)b * H_ + h) * L_ + l0 + r16] = acc[r];
  }
}

// ---------------------------------------------------------------------------
// K3: softmax prologue + cv-quarter via MFMA. (R10 body + nontemporal v)
// grid 2048, block 512 (8 waves). Block = (b = vid>>2, dq = vid&3).
// LDS 8448 B -> 4 blocks/CU x 8 waves = 32 waves/CU.
// ---------------------------------------------------------------------------
__global__ __launch_bounds__(512) void k_cv2(const float* __restrict__ vg,
                                             const float* __restrict__ sc,
                                             __bf16* __restrict__ cv) {
  __shared__ __bf16 wA[H_][L_ + 8];      // weights [h][l], row stride 528B

  int tid = threadIdx.x, lane = tid & 63, wv = tid >> 6;  // wv 0..7
  int r16 = lane & 15, g = lane >> 4;                     // g 0..3
  int vid = blockIdx.x;
  int b = vid >> 2;
  int dq = vid & 3;

  // ---- Softmax: wave wv handles head rows wv*2, wv*2+1; write wA bf16.
  const float* scB = sc + (size_t)b * H_ * L_;
#pragma unroll
  for (int rr = 0; rr < 2; ++rr) {
    int row = wv * 2 + rr;
    const float* srow = scB + (size_t)row * L_;
    float x0 = srow[lane];
    float x1 = srow[lane + 64];
    float x2 = srow[lane + 128];
    float x3 = srow[lane + 192];
    float m = fmaxf(fmaxf(x0, x1), fmaxf(x2, x3));
#pragma unroll
    for (int off = 32; off; off >>= 1) m = fmaxf(m, __shfl_xor(m, off));
    float e0 = __expf(x0 - m), e1 = __expf(x1 - m);
    float e2 = __expf(x2 - m), e3 = __expf(x3 - m);
    float s = e0 + e1 + e2 + e3;
#pragma unroll
    for (int off = 32; off; off >>= 1) s += __shfl_xor(s, off);
    float inv = 1.0f / s;
    wA[row][lane]       = (__bf16)(e0 * inv);
    wA[row][lane + 64]  = (__bf16)(e1 * inv);
    wA[row][lane + 128] = (__bf16)(e2 * inv);
    wA[row][lane + 192] = (__bf16)(e3 * inv);
  }
  __syncthreads();

  // ---- Phase B: wave wv owns d-range [dq*256 + wv*32, +32) = 2 ntiles.
  int dbase = dq * 256 + wv * 32;
  const float* vB = vg + (size_t)b * L_ * D_ + dbase;
  f32x4 acc[2] = {{0.f,0.f,0.f,0.f}, {0.f,0.f,0.f,0.f}};
#pragma unroll 2
  for (int ks = 0; ks < 8; ++ks) {
    int l0 = ks * 32 + g * 8;
    bf16x8 a = *(const bf16x8*)(&wA[r16][l0]);
    const float* pv = vB + (size_t)l0 * D_ + r16;
#pragma unroll
    for (int nt = 0; nt < 2; ++nt) {
      const float* p = pv + nt * 16;
      f32x4 c0, c1;
#pragma unroll
      for (int j = 0; j < 4; ++j) c0[j] = ntl1(p + (size_t)j * D_);
#pragma unroll
      for (int j = 0; j < 4; ++j) c1[j] = ntl1(p + (size_t)(4 + j) * D_);
      acc[nt] = MFMA16(a, cvt8(c0, c1), acc[nt]);
    }
  }
#pragma unroll
  for (int nt = 0; nt < 2; ++nt)
#pragma unroll
    for (int r = 0; r < 4; ++r)
      cv[((size_t)b * H_ + g * 4 + r) * D_ + dbase + nt * 16 + r16] = (__bf16)acc[nt][r];
}

// ---------------------------------------------------------------------------
// K4: ctx[b, h*64+vv] = sum_d cv[b,h,d] * Wv[h,vv,d]
// ---------------------------------------------------------------------------
__global__ __launch_bounds__(256) void k_ctx(const __bf16* __restrict__ cv,
                                             const float* __restrict__ Wv,
                                             __bf16* __restrict__ ctx) {
  int tid = threadIdx.x, lane = tid & 63, wid = tid >> 6;
  int r16 = lane & 15, g = lane >> 4;
  int h = blockIdx.z, m0 = blockIdx.y * 16, n0 = wid * 16;
  const __bf16* arow = cv + (size_t)(m0 + r16) * (H_ * D_) + (size_t)h * D_;
  const float* brow = Wv + (size_t)h * DV_ * D_ + (size_t)(n0 + r16) * D_;
  f32x4 acc = {0.f, 0.f, 0.f, 0.f};
  for (int ks = 0; ks < D_ / 32; ++ks) {
    int k0 = ks * 32 + g * 8;
    bf16x8 a = *(const bf16x8*)(arow + k0);
    f32x4 b0 = *(const f32x4*)(brow + k0);
    f32x4 b1 = *(const f32x4*)(brow + k0 + 4);
    acc = MFMA16(a, cvt8(b0, b1), acc);
  }
#pragma unroll
  for (int r = 0; r < 4; ++r) {
    int m = m0 + g * 4 + r;
    ctx[(size_t)m * (H_ * DV_) + h * DV_ + n0 + r16] = (__bf16)acc[r];
  }
}

// ---------------------------------------------------------------------------
// K5: outp[b,d] = sum_j ctx[b,j] * Wp[d,j] + q[b,d]
// ---------------------------------------------------------------------------
__global__ __launch_bounds__(256) void k_out(const __bf16* __restrict__ ctx,
                                             const float* __restrict__ Wp,
                                             const float* __restrict__ q,
                                             float* __restrict__ outp) {
  int tid = threadIdx.x, lane = tid & 63, wid = tid >> 6;
  int r16 = lane & 15, g = lane >> 4;
  int n0 = (blockIdx.x * 4 + wid) * 16;
  int m0 = blockIdx.y * 16;
  const __bf16* arow = ctx + (size_t)(m0 + r16) * D_;
  const float* brow = Wp + (size_t)(n0 + r16) * D_;
  f32x4 acc = {0.f, 0.f, 0.f, 0.f};
  for (int ks = 0; ks < D_ / 32; ++ks) {
    int k0 = ks * 32 + g * 8;
    bf16x8 a = *(const bf16x8*)(arow + k0);
    f32x4 b0 = *(const f32x4*)(brow + k0);
    f32x4 b1 = *(const f32x4*)(brow + k0 + 4);
    acc = MFMA16(a, cvt8(b0, b1), acc);
  }
#pragma unroll
  for (int r = 0; r < 4; ++r) {
    int m = m0 + g * 4 + r;
    outp[(size_t)m * D_ + n0 + r16] = acc[r] + q[(size_t)m * D_ + n0 + r16];
  }
}

// ---------------------------------------------------------------------------
// K6: LayerNorm, unbiased std (D-1), eps=1 added to STD.
// ---------------------------------------------------------------------------
__global__ __launch_bounds__(256) void k_ln(const float* __restrict__ xin,
                                            const float* __restrict__ scale,
                                            const float* __restrict__ offs,
                                            float* __restrict__ out) {
  __shared__ float red[4];
  int b = blockIdx.x, tid = threadIdx.x;
  const float* row = xin + (size_t)b * D_;
  f32x4 x = *(const f32x4*)(row + tid * 4);
  float s = x[0] + x[1] + x[2] + x[3];
#pragma unroll
  for (int off = 32; off; off >>= 1) s += __shfl_xor(s, off);
  if ((tid & 63) == 0) red[tid >> 6] = s;
  __syncthreads();
  float mean = (red[0] + red[1] + red[2] + red[3]) * (1.0f / D_);
  __syncthreads();  // before reusing red
  float vs = 0.f;
#pragma unroll
  for (int j = 0; j < 4; ++j) { float d = x[j] - mean; vs += d * d; }
#pragma unroll
  for (int off = 32; off; off >>= 1) vs += __shfl_xor(vs, off);
  if ((tid & 63) == 0) red[tid >> 6] = vs;
  __syncthreads();
  float var = (red[0] + red[1] + red[2] + red[3]) * (1.0f / (D_ - 1));
  float inv = 1.0f / (sqrtf(var) + 1.0f);
  f32x4 sc = *(const f32x4*)(scale + tid * 4);
  f32x4 of = *(const f32x4*)(offs + tid * 4);
  f32x4 o;
#pragma unroll
  for (int j = 0; j < 4; ++j) o[j] = sc[j] * (x[j] - mean) * inv + of[j];
  *(f32x4*)(out + (size_t)b * D_ + tid * 4) = o;
}

// ---------------------------------------------------------------------------
extern "C" void kernel_launch(void* const* d_in, const int* in_sizes, int n_in,
                              void* d_out, int out_size, void* d_ws, size_t ws_size,
                              hipStream_t stream) {
  const float* q     = (const float*)d_in[0];
  const float* k     = (const float*)d_in[1];
  const float* v     = (const float*)d_in[2];
  const float* Wq    = (const float*)d_in[3];
  const float* Wk    = (const float*)d_in[4];
  const float* Wv    = (const float*)d_in[5];
  const float* Wp    = (const float*)d_in[6];
  const float* scale = (const float*)d_in[7];
  const float* offs  = (const float*)d_in[8];
  float* out = (float*)d_out;

  // Workspace layout:
  char* ws = (char*)d_ws;
  __bf16* Aq   = (__bf16*)(ws);                          // 16 MB
  float*  scr  = (float*) (ws + (size_t)16 * (1 << 20)); // 8 MB  (raw scores)
  __bf16* cv   = (__bf16*)(ws + (size_t)24 * (1 << 20)); // 16 MB
  __bf16* ctx  = (__bf16*)(ws + (size_t)40 * (1 << 20)); // 1 MB
  float*  outp = (float*) (ws + (size_t)41 * (1 << 20)); // 2 MB

  k_proj <<<dim3(32, 16),     256, 0, stream>>>(q, Wq, Wk, Aq);
  k_score<<<dim3(4, 512),     256, 0, stream>>>(k, Aq, scr);
  k_cv2  <<<dim3(2048),       512, 0, stream>>>(v, scr, cv);
  k_ctx  <<<dim3(1, 32, 16),  256, 0, stream>>>(cv, Wv, ctx);
  k_out  <<<dim3(16, 32),     256, 0, stream>>>(ctx, Wp, q, outp);
  k_ln   <<<dim3(512),        256, 0, stream>>>(outp, scale, offs, out);
}

// Round 13
// 325.089 us; speedup vs baseline: 1.0788x; 1.0788x over previous
//
#include <hip/hip_runtime.h>

// Problem constants
#define B_ 512
#define L_ 256
#define D_ 1024
#define H_ 16
#define DK_ 64
#define DV_ 64
// TEMP = sqrt(1024) = 32 exactly (folded into Aq in k_proj)

typedef float f32x4 __attribute__((ext_vector_type(4)));
typedef float f32x2 __attribute__((ext_vector_type(2)));
typedef __bf16 bf16x8 __attribute__((ext_vector_type(8)));
typedef __bf16 bf16x2 __attribute__((ext_vector_type(2)));

#define MFMA16(a, b, c) __builtin_amdgcn_mfma_f32_16x16x32_bf16((a), (b), (c), 0, 0, 0)

__device__ inline bf16x8 cvt8(f32x4 a, f32x4 b) {
  bf16x8 r;
  r[0] = (__bf16)a[0]; r[1] = (__bf16)a[1]; r[2] = (__bf16)a[2]; r[3] = (__bf16)a[3];
  r[4] = (__bf16)b[0]; r[5] = (__bf16)b[1]; r[6] = (__bf16)b[2]; r[7] = (__bf16)b[3];
  return r;
}

// ---------------------------------------------------------------------------
// K1: fused q-proj + Wk-proj.  grid (32 m-tiles, 16 h), block 256 (4 waves).
// ---------------------------------------------------------------------------
__global__ __launch_bounds__(256) void k_proj(const float* __restrict__ q,
                                              const float* __restrict__ Wq,
                                              const float* __restrict__ Wk,
                                              __bf16* __restrict__ Aq) {
  __shared__ __bf16 hq_lds[16][80];  // row stride 160B (16B-mult)
  int tid = threadIdx.x, lane = tid & 63, wid = tid >> 6;
  int r16 = lane & 15, g = lane >> 4;
  int m0 = blockIdx.x * 16, h = blockIdx.y;

  // ---- Step 1: wave wid computes kk-ntile wid*16
  {
    const float* arow = q  + (size_t)(m0 + r16) * D_;
    const float* brow = Wq + (size_t)(h * DK_ + wid * 16 + r16) * D_;
    f32x4 acc = {0.f, 0.f, 0.f, 0.f};
    for (int ks = 0; ks < D_ / 32; ++ks) {
      int k0 = ks * 32 + g * 8;
      f32x4 a0 = *(const f32x4*)(arow + k0);
      f32x4 a1 = *(const f32x4*)(arow + k0 + 4);
      f32x4 b0 = *(const f32x4*)(brow + k0);
      f32x4 b1 = *(const f32x4*)(brow + k0 + 4);
      acc = MFMA16(cvt8(a0, a1), cvt8(b0, b1), acc);
    }
#pragma unroll
    for (int r = 0; r < 4; ++r)
      hq_lds[g * 4 + r][wid * 16 + r16] = (__bf16)acc[r];
  }
  __syncthreads();

  // ---- Step 2: wave wid owns d-cols [wid*256, +256) = 16 ntiles
  const float* bcolBase = Wk + (size_t)h * DK_ * D_;
  for (int nt = 0; nt < 16; ++nt) {
    int n0 = wid * 256 + nt * 16;
    const float* bcol = bcolBase + n0 + r16;  // + k*D_
    f32x4 acc = {0.f, 0.f, 0.f, 0.f};
#pragma unroll
    for (int ks = 0; ks < 2; ++ks) {
      int k0 = ks * 32 + g * 8;
      bf16x8 a = *(const bf16x8*)(&hq_lds[r16][k0]);
      f32x4 c0, c1;
#pragma unroll
      for (int j = 0; j < 4; ++j) c0[j] = bcol[(size_t)(k0 + j) * D_];
#pragma unroll
      for (int j = 0; j < 4; ++j) c1[j] = bcol[(size_t)(k0 + 4 + j) * D_];
      acc = MFMA16(a, cvt8(c0, c1), acc);
    }
#pragma unroll
    for (int r = 0; r < 4; ++r) {
      int m = m0 + g * 4 + r;
      Aq[(size_t)m * (H_ * D_) + (size_t)h * D_ + n0 + r16] = (__bf16)(acc[r] * 0.03125f);
    }
  }
}

// ---------------------------------------------------------------------------
// K2: scores via row-linear staged k (burst test at FULL occupancy).
// grid (4, 512): x = l-quarter (64 rows), y = b. block 256 (4 waves).
// 8 chunks of 128 cols: stage [64 rows][128 cols] -> LDS bf16 (one-row 512B
// contiguous per instruction, f32x2/lane), then 4 MFMA/wave from LDS.
// LDS 64x136 bf16 = 17.4KB -> 8 blocks/CU x 4 waves = 32 waves/CU (FULL).
// ---------------------------------------------------------------------------
__global__ __launch_bounds__(256) void k_score(const float* __restrict__ kg,
                                               const __bf16* __restrict__ Aq,
                                               float* __restrict__ sc) {
  __shared__ __bf16 kT[64][136];   // row stride 272B (16B-mult; 2-way banks)

  int tid = threadIdx.x, lane = tid & 63, wv = tid >> 6;
  int r16 = lane & 15, g = lane >> 4;
  int b = blockIdx.y;
  int l0 = blockIdx.x * 64;
  const __bf16* AqB = Aq + (size_t)b * H_ * D_;
  const float*  kB  = kg + ((size_t)b * L_ + l0) * D_;

  f32x4 acc = {0.f, 0.f, 0.f, 0.f};

  for (int cs = 0; cs < 8; ++cs) {
    // ---- stage chunk [64 rows][cs*128 .. +128): one row = one 512B burst
    {
      const float* src = kB + cs * 128 + lane * 2;
#pragma unroll
      for (int rr = 0; rr < 16; ++rr) {
        int row = wv * 16 + rr;
        f32x2 x = *(const f32x2*)(src + (size_t)row * D_);
        bf16x2 y;
        y[0] = (__bf16)x[0]; y[1] = (__bf16)x[1];
        *(bf16x2*)(&kT[row][lane * 2]) = y;
      }
    }
    __syncthreads();

    // ---- mfma: wave wv owns ltile wv (rows wv*16..+16), 4 k-slices
    const __bf16* aR = AqB + (size_t)r16 * D_ + cs * 128;
#pragma unroll
    for (int ks = 0; ks < 4; ++ks) {
      bf16x8 a  = *(const bf16x8*)(aR + ks * 32 + g * 8);
      bf16x8 kf = *(const bf16x8*)(&kT[wv * 16 + r16][ks * 32 + g * 8]);
      acc = MFMA16(a, kf, acc);
    }
    __syncthreads();
  }

#pragma unroll
  for (int r = 0; r < 4; ++r) {
    int h = g * 4 + r;
    sc[((size_t)b * H_ + h) * L_ + l0 + wv * 16 + r16] = acc[r];
  }
}

// ---------------------------------------------------------------------------
// K3: softmax prologue (from global sc) + cv-quarter via MFMA. (R10-verbatim)
// grid 2048, block 512 (8 waves). Block = (b = vid>>2, dq = vid&3).
// LDS 8448 B -> 4 blocks/CU x 8 waves = 32 waves/CU.
// ---------------------------------------------------------------------------
__global__ __launch_bounds__(512) void k_cv2(const float* __restrict__ vg,
                                             const float* __restrict__ sc,
                                             __bf16* __restrict__ cv) {
  __shared__ __bf16 wA[H_][L_ + 8];      // weights [h][l], row stride 528B

  int tid = threadIdx.x, lane = tid & 63, wv = tid >> 6;  // wv 0..7
  int r16 = lane & 15, g = lane >> 4;                     // g 0..3
  int vid = blockIdx.x;
  int b = vid >> 2;
  int dq = vid & 3;

  // ---- Softmax: wave wv handles head rows wv*2, wv*2+1; write wA bf16.
  const float* scB = sc + (size_t)b * H_ * L_;
#pragma unroll
  for (int rr = 0; rr < 2; ++rr) {
    int row = wv * 2 + rr;
    const float* srow = scB + (size_t)row * L_;
    float x0 = srow[lane];
    float x1 = srow[lane + 64];
    float x2 = srow[lane + 128];
    float x3 = srow[lane + 192];
    float m = fmaxf(fmaxf(x0, x1), fmaxf(x2, x3));
#pragma unroll
    for (int off = 32; off; off >>= 1) m = fmaxf(m, __shfl_xor(m, off));
    float e0 = __expf(x0 - m), e1 = __expf(x1 - m);
    float e2 = __expf(x2 - m), e3 = __expf(x3 - m);
    float s = e0 + e1 + e2 + e3;
#pragma unroll
    for (int off = 32; off; off >>= 1) s += __shfl_xor(s, off);
    float inv = 1.0f / s;
    wA[row][lane]       = (__bf16)(e0 * inv);
    wA[row][lane + 64]  = (__bf16)(e1 * inv);
    wA[row][lane + 128] = (__bf16)(e2 * inv);
    wA[row][lane + 192] = (__bf16)(e3 * inv);
  }
  __syncthreads();

  // ---- Phase B: wave wv owns d-range [dq*256 + wv*32, +32) = 2 ntiles.
  int dbase = dq * 256 + wv * 32;
  const float* vB = vg + (size_t)b * L_ * D_ + dbase;
  f32x4 acc[2] = {{0.f,0.f,0.f,0.f}, {0.f,0.f,0.f,0.f}};
#pragma unroll 2
  for (int ks = 0; ks < 8; ++ks) {
    int l0 = ks * 32 + g * 8;
    bf16x8 a = *(const bf16x8*)(&wA[r16][l0]);
    const float* pv = vB + (size_t)l0 * D_ + r16;
#pragma unroll
    for (int nt = 0; nt < 2; ++nt) {
      const float* p = pv + nt * 16;
      f32x4 c0, c1;
#pragma unroll
      for (int j = 0; j < 4; ++j) c0[j] = p[(size_t)j * D_];
#pragma unroll
      for (int j = 0; j < 4; ++j) c1[j] = p[(size_t)(4 + j) * D_];
      acc[nt] = MFMA16(a, cvt8(c0, c1), acc[nt]);
    }
  }
#pragma unroll
  for (int nt = 0; nt < 2; ++nt)
#pragma unroll
    for (int r = 0; r < 4; ++r)
      cv[((size_t)b * H_ + g * 4 + r) * D_ + dbase + nt * 16 + r16] = (__bf16)acc[nt][r];
}

// ---------------------------------------------------------------------------
// K4: ctx[b, h*64+vv] = sum_d cv[b,h,d] * Wv[h,vv,d]
// ---------------------------------------------------------------------------
__global__ __launch_bounds__(256) void k_ctx(const __bf16* __restrict__ cv,
                                             const float* __restrict__ Wv,
                                             __bf16* __restrict__ ctx) {
  int tid = threadIdx.x, lane = tid & 63, wid = tid >> 6;
  int r16 = lane & 15, g = lane >> 4;
  int h = blockIdx.z, m0 = blockIdx.y * 16, n0 = wid * 16;
  const __bf16* arow = cv + (size_t)(m0 + r16) * (H_ * D_) + (size_t)h * D_;
  const float* brow = Wv + (size_t)h * DV_ * D_ + (size_t)(n0 + r16) * D_;
  f32x4 acc = {0.f, 0.f, 0.f, 0.f};
  for (int ks = 0; ks < D_ / 32; ++ks) {
    int k0 = ks * 32 + g * 8;
    bf16x8 a = *(const bf16x8*)(arow + k0);
    f32x4 b0 = *(const f32x4*)(brow + k0);
    f32x4 b1 = *(const f32x4*)(brow + k0 + 4);
    acc = MFMA16(a, cvt8(b0, b1), acc);
  }
#pragma unroll
  for (int r = 0; r < 4; ++r) {
    int m = m0 + g * 4 + r;
    ctx[(size_t)m * (H_ * DV_) + h * DV_ + n0 + r16] = (__bf16)acc[r];
  }
}

// ---------------------------------------------------------------------------
// K5: outp[b,d] = sum_j ctx[b,j] * Wp[d,j] + q[b,d]
// ---------------------------------------------------------------------------
__global__ __launch_bounds__(256) void k_out(const __bf16* __restrict__ ctx,
                                             const float* __restrict__ Wp,
                                             const float* __restrict__ q,
                                             float* __restrict__ outp) {
  int tid = threadIdx.x, lane = tid & 63, wid = tid >> 6;
  int r16 = lane & 15, g = lane >> 4;
  int n0 = (blockIdx.x * 4 + wid) * 16;
  int m0 = blockIdx.y * 16;
  const __bf16* arow = ctx + (size_t)(m0 + r16) * D_;
  const float* brow = Wp + (size_t)(n0 + r16) * D_;
  f32x4 acc = {0.f, 0.f, 0.f, 0.f};
  for (int ks = 0; ks < D_ / 32; ++ks) {
    int k0 = ks * 32 + g * 8;
    bf16x8 a = *(const bf16x8*)(arow + k0);
    f32x4 b0 = *(const f32x4*)(brow + k0);
    f32x4 b1 = *(const f32x4*)(brow + k0 + 4);
    acc = MFMA16(a, cvt8(b0, b1), acc);
  }
#pragma unroll
  for (int r = 0; r < 4; ++r) {
    int m = m0 + g * 4 + r;
    outp[(size_t)m * D_ + n0 + r16] = acc[r] + q[(size_t)m * D_ + n0 + r16];
  }
}

// ---------------------------------------------------------------------------
// K6: LayerNorm, unbiased std (D-1), eps=1 added to STD.
// ---------------------------------------------------------------------------
__global__ __launch_bounds__(256) void k_ln(const float* __restrict__ xin,
                                            const float* __restrict__ scale,
                                            const float* __restrict__ offs,
                                            float* __restrict__ out) {
  __shared__ float red[4];
  int b = blockIdx.x, tid = threadIdx.x;
  const float* row = xin + (size_t)b * D_;
  f32x4 x = *(const f32x4*)(row + tid * 4);
  float s = x[0] + x[1] + x[2] + x[3];
#pragma unroll
  for (int off = 32; off; off >>= 1) s += __shfl_xor(s, off);
  if ((tid & 63) == 0) red[tid >> 6] = s;
  __syncthreads();
  float mean = (red[0] + red[1] + red[2] + red[3]) * (1.0f / D_);
  __syncthreads();  // before reusing red
  float vs = 0.f;
#pragma unroll
  for (int j = 0; j < 4; ++j) { float d = x[j] - mean; vs += d * d; }
#pragma unroll
  for (int off = 32; off; off >>= 1) vs += __shfl_xor(vs, off);
  if ((tid & 63) == 0) red[tid >> 6] = vs;
  __syncthreads();
  float var = (red[0] + red[1] + red[2] + red[3]) * (1.0f / (D_ - 1));
  float inv = 1.0f / (sqrtf(var) + 1.0f);
  f32x4 sc = *(const f32x4*)(scale + tid * 4);
  f32x4 of = *(const f32x4*)(offs + tid * 4);
  f32x4 o;
#pragma unroll
  for (int j = 0; j < 4; ++j) o[j] = sc[j] * (x[j] - mean) * inv + of[j];
  *(f32x4*)(out + (size_t)b * D_ + tid * 4) = o;
}

// ---------------------------------------------------------------------------
extern "C" void kernel_launch(void* const* d_in, const int* in_sizes, int n_in,
                              void* d_out, int out_size, void* d_ws, size_t ws_size,
                              hipStream_t stream) {
  const float* q     = (const float*)d_in[0];
  const float* k     = (const float*)d_in[1];
  const float* v     = (const float*)d_in[2];
  const float* Wq    = (const float*)d_in[3];
  const float* Wk    = (const float*)d_in[4];
  const float* Wv    = (const float*)d_in[5];
  const float* Wp    = (const float*)d_in[6];
  const float* scale = (const float*)d_in[7];
  const float* offs  = (const float*)d_in[8];
  float* out = (float*)d_out;

  // Workspace layout:
  char* ws = (char*)d_ws;
  __bf16* Aq   = (__bf16*)(ws);                          // 16 MB
  float*  scr  = (float*) (ws + (size_t)16 * (1 << 20)); // 8 MB  (raw scores)
  __bf16* cv   = (__bf16*)(ws + (size_t)24 * (1 << 20)); // 16 MB
  __bf16* ctx  = (__bf16*)(ws + (size_t)40 * (1 << 20)); // 1 MB
  float*  outp = (float*) (ws + (size_t)41 * (1 << 20)); // 2 MB

  k_proj <<<dim3(32, 16),     256, 0, stream>>>(q, Wq, Wk, Aq);
  k_score<<<dim3(4, 512),     256, 0, stream>>>(k, Aq, scr);
  k_cv2  <<<dim3(2048),       512, 0, stream>>>(v, scr, cv);
  k_ctx  <<<dim3(1, 32, 16),  256, 0, stream>>>(cv, Wv, ctx);
  k_out  <<<dim3(16, 32),     256, 0, stream>>>(ctx, Wp, q, outp);
  k_ln   <<<dim3(512),        256, 0, stream>>>(outp, scale, offs, out);
}

// Round 14
// 313.327 us; speedup vs baseline: 1.1193x; 1.0375x over previous
//
#include <hip/hip_runtime.h>

// Problem constants
#define B_ 512
#define L_ 256
#define D_ 1024
#define H_ 16
#define DK_ 64
#define DV_ 64
// TEMP = sqrt(1024) = 32 exactly (folded into Aq in k_proj)

typedef float f32x4 __attribute__((ext_vector_type(4)));
typedef __bf16 bf16x8 __attribute__((ext_vector_type(8)));

#define MFMA16(a, b, c) __builtin_amdgcn_mfma_f32_16x16x32_bf16((a), (b), (c), 0, 0, 0)

__device__ inline bf16x8 cvt8(f32x4 a, f32x4 b) {
  bf16x8 r;
  r[0] = (__bf16)a[0]; r[1] = (__bf16)a[1]; r[2] = (__bf16)a[2]; r[3] = (__bf16)a[3];
  r[4] = (__bf16)b[0]; r[5] = (__bf16)b[1]; r[6] = (__bf16)b[2]; r[7] = (__bf16)b[3];
  return r;
}

// ---------------------------------------------------------------------------
// K1: fused q-proj + Wk-proj.  grid (32 m-tiles, 16 h), block 256 (4 waves).
//   Step 1: hq_t[16,64] = q[m0:16,:] . Wq[h*64:+64,:]^T   (K=1024) -> LDS bf16
//   Step 2: Aq[m0:16, h, :] = (1/32) * hq_t . Wk[h]       (K=64)
// ---------------------------------------------------------------------------
__global__ __launch_bounds__(256) void k_proj(const float* __restrict__ q,
                                              const float* __restrict__ Wq,
                                              const float* __restrict__ Wk,
                                              __bf16* __restrict__ Aq) {
  __shared__ __bf16 hq_lds[16][80];  // row stride 160B (16B-mult)
  int tid = threadIdx.x, lane = tid & 63, wid = tid >> 6;
  int r16 = lane & 15, g = lane >> 4;
  int m0 = blockIdx.x * 16, h = blockIdx.y;

  // ---- Step 1: wave wid computes kk-ntile wid*16
  {
    const float* arow = q  + (size_t)(m0 + r16) * D_;
    const float* brow = Wq + (size_t)(h * DK_ + wid * 16 + r16) * D_;
    f32x4 acc = {0.f, 0.f, 0.f, 0.f};
    for (int ks = 0; ks < D_ / 32; ++ks) {
      int k0 = ks * 32 + g * 8;
      f32x4 a0 = *(const f32x4*)(arow + k0);
      f32x4 a1 = *(const f32x4*)(arow + k0 + 4);
      f32x4 b0 = *(const f32x4*)(brow + k0);
      f32x4 b1 = *(const f32x4*)(brow + k0 + 4);
      acc = MFMA16(cvt8(a0, a1), cvt8(b0, b1), acc);
    }
#pragma unroll
    for (int r = 0; r < 4; ++r)
      hq_lds[g * 4 + r][wid * 16 + r16] = (__bf16)acc[r];
  }
  __syncthreads();

  // ---- Step 2: wave wid owns d-cols [wid*256, +256) = 16 ntiles
  const float* bcolBase = Wk + (size_t)h * DK_ * D_;
  for (int nt = 0; nt < 16; ++nt) {
    int n0 = wid * 256 + nt * 16;
    const float* bcol = bcolBase + n0 + r16;  // + k*D_
    f32x4 acc = {0.f, 0.f, 0.f, 0.f};
#pragma unroll
    for (int ks = 0; ks < 2; ++ks) {
      int k0 = ks * 32 + g * 8;
      bf16x8 a = *(const bf16x8*)(&hq_lds[r16][k0]);
      f32x4 c0, c1;
#pragma unroll
      for (int j = 0; j < 4; ++j) c0[j] = bcol[(size_t)(k0 + j) * D_];
#pragma unroll
      for (int j = 0; j < 4; ++j) c1[j] = bcol[(size_t)(k0 + 4 + j) * D_];
      acc = MFMA16(a, cvt8(c0, c1), acc);
    }
#pragma unroll
    for (int r = 0; r < 4; ++r) {
      int m = m0 + g * 4 + r;
      Aq[(size_t)m * (H_ * D_) + (size_t)h * D_ + n0 + r16] = (__bf16)(acc[r] * 0.03125f);
    }
  }
}

// ---------------------------------------------------------------------------
// K2: scores[b, h, l] = Aq[b,h,:] . k[b,l,:]   (temp already folded into Aq)
// 1-D grid 2048, XCD-swizzled so each b's 4 blocks share one XCD's L2.
// block 256 (4 waves), 8 blocks/CU x 4 waves = 32 waves/CU.
// ---------------------------------------------------------------------------
__global__ __launch_bounds__(256) void k_score(const float* __restrict__ kg,
                                               const __bf16* __restrict__ Aq,
                                               float* __restrict__ sc) {
  int tid = threadIdx.x, lane = tid & 63, wv = tid >> 6;
  int r16 = lane & 15, g = lane >> 4;
  // bijective XCD swizzle: 2048 % 8 == 0
  int wg = blockIdx.x;
  int vid = (wg & 7) * 256 + (wg >> 3);
  int b = vid >> 2;             // 0..511
  int lq = vid & 3;             // l-quarter
  int l0 = lq * 64 + wv * 16;
  const __bf16* AqB = Aq + (size_t)b * H_ * D_;
  const float*  kR  = kg + ((size_t)b * L_ + l0 + r16) * D_;
  f32x4 acc = {0.f, 0.f, 0.f, 0.f};
#pragma unroll 4
  for (int ks = 0; ks < D_ / 32; ++ks) {
    int k0 = ks * 32 + g * 8;
    bf16x8 a = *(const bf16x8*)(AqB + (size_t)r16 * D_ + k0);
    f32x4 b0 = *(const f32x4*)(kR + k0);
    f32x4 b1 = *(const f32x4*)(kR + k0 + 4);
    acc = MFMA16(a, cvt8(b0, b1), acc);
  }
#pragma unroll
  for (int r = 0; r < 4; ++r) {
    int h = g * 4 + r;
    sc[((size_t)b * H_ + h) * L_ + l0 + r16] = acc[r];
  }
}

// ---------------------------------------------------------------------------
// K3: softmax prologue + cv[16,1024] = w[16,256] * v[256,1024] via MFMA.
// 1-D grid 2048, XCD-swizzled (sc[b] shared by 4 blocks). block 256 (4 waves).
// Wave wv owns d-range [dq*256 + wv*64, +64) = 4 ntiles, full K=L=256.
// ---------------------------------------------------------------------------
__global__ __launch_bounds__(256) void k_cv(const float* __restrict__ vg,
                                            const float* __restrict__ sc,
                                            __bf16* __restrict__ cv) {
  __shared__ __bf16 wA[H_][L_ + 8];  // w[h][l], row stride 528B (16B-mult)

  int tid = threadIdx.x, lane = tid & 63, wv = tid >> 6;
  int r16 = lane & 15, g = (lane >> 4) & 3;
  int wg = blockIdx.x;
  int vid = (wg & 7) * 256 + (wg >> 3);
  int b = vid >> 2;
  int dq = vid & 3;

  // ---- softmax: wave wv handles head rows wv*4 .. wv*4+3
  const float* scB = sc + (size_t)b * H_ * L_;
#pragma unroll
  for (int rr = 0; rr < 4; ++rr) {
    int row = wv * 4 + rr;
    const float* srow = scB + (size_t)row * L_;
    float x0 = srow[lane], x1 = srow[lane + 64];
    float x2 = srow[lane + 128], x3 = srow[lane + 192];
    float m = fmaxf(fmaxf(x0, x1), fmaxf(x2, x3));
#pragma unroll
    for (int off = 32; off; off >>= 1) m = fmaxf(m, __shfl_xor(m, off));
    float e0 = __expf(x0 - m), e1 = __expf(x1 - m);
    float e2 = __expf(x2 - m), e3 = __expf(x3 - m);
    float s = e0 + e1 + e2 + e3;
#pragma unroll
    for (int off = 32; off; off >>= 1) s += __shfl_xor(s, off);
    float inv = 1.0f / s;
    wA[row][lane]       = (__bf16)(e0 * inv);
    wA[row][lane + 64]  = (__bf16)(e1 * inv);
    wA[row][lane + 128] = (__bf16)(e2 * inv);
    wA[row][lane + 192] = (__bf16)(e3 * inv);
  }
  __syncthreads();

  // ---- main: 4 ntiles x 8 k-slices of MFMA, v loaded direct from global.
  int dbase = dq * 256 + wv * 64;
  const float* vB = vg + (size_t)b * L_ * D_ + dbase;
  f32x4 acc[4] = {{0.f,0.f,0.f,0.f},{0.f,0.f,0.f,0.f},
                  {0.f,0.f,0.f,0.f},{0.f,0.f,0.f,0.f}};
#pragma unroll 2
  for (int ks = 0; ks < 8; ++ks) {
    int l0 = ks * 32 + g * 8;
    bf16x8 a = *(const bf16x8*)(&wA[r16][l0]);
    const float* pv = vB + (size_t)l0 * D_ + r16;
#pragma unroll
    for (int nt = 0; nt < 4; ++nt) {
      const float* p = pv + nt * 16;
      f32x4 c0, c1;
#pragma unroll
      for (int j = 0; j < 4; ++j) c0[j] = p[(size_t)j * D_];
#pragma unroll
      for (int j = 0; j < 4; ++j) c1[j] = p[(size_t)(4 + j) * D_];
      acc[nt] = MFMA16(a, cvt8(c0, c1), acc[nt]);
    }
  }
#pragma unroll
  for (int nt = 0; nt < 4; ++nt)
#pragma unroll
    for (int r = 0; r < 4; ++r)
      cv[((size_t)b * H_ + g * 4 + r) * D_ + dbase + nt * 16 + r16] = (__bf16)acc[nt][r];
}

// ---------------------------------------------------------------------------
// K4: ctx[b, h*64+vv] = sum_d cv[b,h,d] * Wv[h,vv,d]
// ---------------------------------------------------------------------------
__global__ __launch_bounds__(256) void k_ctx(const __bf16* __restrict__ cv,
                                             const float* __restrict__ Wv,
                                             __bf16* __restrict__ ctx) {
  int tid = threadIdx.x, lane = tid & 63, wid = tid >> 6;
  int r16 = lane & 15, g = lane >> 4;
  int h = blockIdx.z, m0 = blockIdx.y * 16, n0 = wid * 16;
  const __bf16* arow = cv + (size_t)(m0 + r16) * (H_ * D_) + (size_t)h * D_;
  const float* brow = Wv + (size_t)h * DV_ * D_ + (size_t)(n0 + r16) * D_;
  f32x4 acc = {0.f, 0.f, 0.f, 0.f};
  for (int ks = 0; ks < D_ / 32; ++ks) {
    int k0 = ks * 32 + g * 8;
    bf16x8 a = *(const bf16x8*)(arow + k0);
    f32x4 b0 = *(const f32x4*)(brow + k0);
    f32x4 b1 = *(const f32x4*)(brow + k0 + 4);
    acc = MFMA16(a, cvt8(b0, b1), acc);
  }
#pragma unroll
  for (int r = 0; r < 4; ++r) {
    int m = m0 + g * 4 + r;
    ctx[(size_t)m * (H_ * DV_) + h * DV_ + n0 + r16] = (__bf16)acc[r];
  }
}

// ---------------------------------------------------------------------------
// K5: outp[b,d] = sum_j ctx[b,j] * Wp[d,j] + q[b,d]
// ---------------------------------------------------------------------------
__global__ __launch_bounds__(256) void k_out(const __bf16* __restrict__ ctx,
                                             const float* __restrict__ Wp,
                                             const float* __restrict__ q,
                                             float* __restrict__ outp) {
  int tid = threadIdx.x, lane = tid & 63, wid = tid >> 6;
  int r16 = lane & 15, g = lane >> 4;
  int n0 = (blockIdx.x * 4 + wid) * 16;
  int m0 = blockIdx.y * 16;
  const __bf16* arow = ctx + (size_t)(m0 + r16) * D_;
  const float* brow = Wp + (size_t)(n0 + r16) * D_;
  f32x4 acc = {0.f, 0.f, 0.f, 0.f};
  for (int ks = 0; ks < D_ / 32; ++ks) {
    int k0 = ks * 32 + g * 8;
    bf16x8 a = *(const bf16x8*)(arow + k0);
    f32x4 b0 = *(const f32x4*)(brow + k0);
    f32x4 b1 = *(const f32x4*)(brow + k0 + 4);
    acc = MFMA16(a, cvt8(b0, b1), acc);
  }
#pragma unroll
  for (int r = 0; r < 4; ++r) {
    int m = m0 + g * 4 + r;
    outp[(size_t)m * D_ + n0 + r16] = acc[r] + q[(size_t)m * D_ + n0 + r16];
  }
}

// ---------------------------------------------------------------------------
// K6: LayerNorm, unbiased std (D-1), eps=1 added to STD.
// ---------------------------------------------------------------------------
__global__ __launch_bounds__(256) void k_ln(const float* __restrict__ xin,
                                            const float* __restrict__ scale,
                                            const float* __restrict__ offs,
                                            float* __restrict__ out) {
  __shared__ float red[4];
  int b = blockIdx.x, tid = threadIdx.x;
  const float* row = xin + (size_t)b * D_;
  f32x4 x = *(const f32x4*)(row + tid * 4);
  float s = x[0] + x[1] + x[2] + x[3];
#pragma unroll
  for (int off = 32; off; off >>= 1) s += __shfl_xor(s, off);
  if ((tid & 63) == 0) red[tid >> 6] = s;
  __syncthreads();
  float mean = (red[0] + red[1] + red[2] + red[3]) * (1.0f / D_);
  __syncthreads();  // before reusing red
  float vs = 0.f;
#pragma unroll
  for (int j = 0; j < 4; ++j) { float d = x[j] - mean; vs += d * d; }
#pragma unroll
  for (int off = 32; off; off >>= 1) vs += __shfl_xor(vs, off);
  if ((tid & 63) == 0) red[tid >> 6] = vs;
  __syncthreads();
  float var = (red[0] + red[1] + red[2] + red[3]) * (1.0f / (D_ - 1));
  float inv = 1.0f / (sqrtf(var) + 1.0f);
  f32x4 sc = *(const f32x4*)(scale + tid * 4);
  f32x4 of = *(const f32x4*)(offs + tid * 4);
  f32x4 o;
#pragma unroll
  for (int j = 0; j < 4; ++j) o[j] = sc[j] * (x[j] - mean) * inv + of[j];
  *(f32x4*)(out + (size_t)b * D_ + tid * 4) = o;
}

// ---------------------------------------------------------------------------
extern "C" void kernel_launch(void* const* d_in, const int* in_sizes, int n_in,
                              void* d_out, int out_size, void* d_ws, size_t ws_size,
                              hipStream_t stream) {
  const float* q     = (const float*)d_in[0];
  const float* k     = (const float*)d_in[1];
  const float* v     = (const float*)d_in[2];
  const float* Wq    = (const float*)d_in[3];
  const float* Wk    = (const float*)d_in[4];
  const float* Wv    = (const float*)d_in[5];
  const float* Wp    = (const float*)d_in[6];
  const float* scale = (const float*)d_in[7];
  const float* offs  = (const float*)d_in[8];
  float* out = (float*)d_out;

  // Workspace layout:
  char* ws = (char*)d_ws;
  __bf16* Aq   = (__bf16*)(ws);                          // 16 MB
  float*  scr  = (float*) (ws + (size_t)16 * (1 << 20)); // 8 MB  (raw scores)
  __bf16* cv   = (__bf16*)(ws + (size_t)24 * (1 << 20)); // 16 MB
  __bf16* ctx  = (__bf16*)(ws + (size_t)40 * (1 << 20)); // 1 MB
  float*  outp = (float*) (ws + (size_t)41 * (1 << 20)); // 2 MB

  k_proj <<<dim3(32, 16),     256, 0, stream>>>(q, Wq, Wk, Aq);
  k_score<<<dim3(2048),       256, 0, stream>>>(k, Aq, scr);
  k_cv   <<<dim3(2048),       256, 0, stream>>>(v, scr, cv);
  k_ctx  <<<dim3(1, 32, 16),  256, 0, stream>>>(cv, Wv, ctx);
  k_out  <<<dim3(16, 32),     256, 0, stream>>>(ctx, Wp, q, outp);
  k_ln   <<<dim3(512),        256, 0, stream>>>(outp, scale, offs, out);
}